// Round 1
// baseline (606.867 us; speedup 1.0000x reference)
//
#include <hip/hip_runtime.h>
#include <hip/hip_bf16.h>
#include <math.h>

#define NNODES 4096
#define NHEADS 4
#define FDIM 256
#define MAXDEG 128

// ---------------- CSR build with bitmap dedupe ----------------
__global__ __launch_bounds__(256) void build_csr(
    const int* __restrict__ er, const int* __restrict__ ec,
    unsigned int* __restrict__ bitmap, int* __restrict__ cnt,
    int* __restrict__ cols, int E)
{
    int e = blockIdx.x * 256 + threadIdx.x;
    if (e >= E) return;
    int r = er[e], c = ec[e];
    unsigned int idx = ((unsigned int)r << 12) | (unsigned int)c; // r*4096+c
    unsigned int bit = 1u << (idx & 31);
    unsigned int old = atomicOr(&bitmap[idx >> 5], bit);
    if (!(old & bit)) {
        int slot = atomicAdd(&cnt[r], 1);
        if (slot < MAXDEG) cols[r * MAXDEG + slot] = c;
    }
}

// ---------------- fp32 SGEMM, 64x64 tile, head-packed B ----------------
// C[M,NH] = A[M,K] @ W, where col j of W lives at W[(j>>8)*K*256 + k*256 + (j&255)]
// (works for single matrices with NH<=256 too: head==0)
__global__ __launch_bounds__(256) void gemm_heads(
    const float* __restrict__ A, const float* __restrict__ W,
    const float* __restrict__ bias, float* __restrict__ C,
    int M, int K, int NH)
{
    __shared__ float As[16][65];
    __shared__ float Bs[16][65];
    int bm = blockIdx.y, bn = blockIdx.x;
    int tid = threadIdx.x;
    int tr = tid >> 4, tc = tid & 15;
    int row0 = bm * 64 + tr * 4;
    int col0 = bn * 64 + tc * 4;
    float acc[4][4] = {};

    int ar = tid >> 2;              // 0..63
    int akk = (tid & 3) * 4;        // 0,4,8,12
    int bk_ = tid >> 4;             // 0..15
    int bc = (tid & 15) * 4;        // 0..60
    int j = bn * 64 + bc;
    int head = j >> 8;
    int jj = j & 255;

    for (int k0 = 0; k0 < K; k0 += 16) {
        float4 av = *(const float4*)(A + (size_t)(bm * 64 + ar) * K + k0 + akk);
        As[akk + 0][ar] = av.x; As[akk + 1][ar] = av.y;
        As[akk + 2][ar] = av.z; As[akk + 3][ar] = av.w;
        float4 bv = *(const float4*)(W + (size_t)head * K * 256 + (size_t)(k0 + bk_) * 256 + jj);
        Bs[bk_][bc + 0] = bv.x; Bs[bk_][bc + 1] = bv.y;
        Bs[bk_][bc + 2] = bv.z; Bs[bk_][bc + 3] = bv.w;
        __syncthreads();
#pragma unroll
        for (int kk = 0; kk < 16; ++kk) {
            float a0 = As[kk][tr * 4 + 0], a1 = As[kk][tr * 4 + 1];
            float a2 = As[kk][tr * 4 + 2], a3 = As[kk][tr * 4 + 3];
            float b0 = Bs[kk][tc * 4 + 0], b1 = Bs[kk][tc * 4 + 1];
            float b2 = Bs[kk][tc * 4 + 2], b3 = Bs[kk][tc * 4 + 3];
            acc[0][0] += a0 * b0; acc[0][1] += a0 * b1; acc[0][2] += a0 * b2; acc[0][3] += a0 * b3;
            acc[1][0] += a1 * b0; acc[1][1] += a1 * b1; acc[1][2] += a1 * b2; acc[1][3] += a1 * b3;
            acc[2][0] += a2 * b0; acc[2][1] += a2 * b1; acc[2][2] += a2 * b2; acc[2][3] += a2 * b3;
            acc[3][0] += a3 * b0; acc[3][1] += a3 * b1; acc[3][2] += a3 * b2; acc[3][3] += a3 * b3;
        }
        __syncthreads();
    }
#pragma unroll
    for (int i = 0; i < 4; ++i)
#pragma unroll
        for (int jq = 0; jq < 4; ++jq) {
            float v = acc[i][jq];
            if (bias) v += bias[(col0 + jq) & 255];
            C[(size_t)(row0 + i) * NH + col0 + jq] = v;
        }
}

// ---------------- wh1/wh2: per (row, head) dot(h_row, a) ----------------
__global__ __launch_bounds__(256) void wh_kernel(
    const float* __restrict__ h_all, const float* __restrict__ a,
    float* __restrict__ wh1, float* __restrict__ wh2, int N)
{
    int i = blockIdx.x;
    int t = threadIdx.x;
    __shared__ float red[8];
    for (int hh = 0; hh < NHEADS; ++hh) {
        float v = h_all[(size_t)i * 1024 + hh * 256 + t];
        float p1 = v * a[hh * 512 + t];
        float p2 = v * a[hh * 512 + 256 + t];
        for (int o = 32; o > 0; o >>= 1) {
            p1 += __shfl_down(p1, o);
            p2 += __shfl_down(p2, o);
        }
        if ((t & 63) == 0) { red[t >> 6] = p1; red[4 + (t >> 6)] = p2; }
        __syncthreads();
        if (t == 0) {
            wh1[hh * N + i] = red[0] + red[1] + red[2] + red[3];
            wh2[hh * N + i] = red[4] + red[5] + red[6] + red[7];
        }
        __syncthreads();
    }
}

// ---------------- column sums of h_all ----------------
__global__ __launch_bounds__(256) void colsum_kernel(
    const float* __restrict__ h_all, float* __restrict__ colsum, int N)
{
    int c = blockIdx.x * 256 + threadIdx.x;   // gridDim.x = 4 -> 1024 cols
    int r0 = blockIdx.y * 128;
    float s = 0.f;
    for (int r = r0; r < r0 + 128; ++r) s += h_all[(size_t)r * 1024 + c];
    atomicAdd(&colsum[c], s);
}

// ---------------- per-row attention + normalize + head-mean + residual + elu ----------------
__global__ __launch_bounds__(256) void row_attn(
    const float* __restrict__ h_all, const float* __restrict__ wh1,
    const float* __restrict__ wh2, const float* __restrict__ colsum,
    const int* __restrict__ cnt, const int* __restrict__ cols,
    const float* __restrict__ bias, const float* __restrict__ prev,
    float* __restrict__ outp, int N)
{
    int i = blockIdx.x;
    int t = threadIdx.x;
    __shared__ int colsS[MAXDEG];
    __shared__ float wS[MAXDEG];
    __shared__ float red[4];
    int deg = cnt[i];
    if (deg > MAXDEG) deg = MAXDEG;
    if (t < deg) colsS[t] = cols[i * MAXDEG + t];
    __syncthreads();

    float hsum = 0.f;
    for (int hh = 0; hh < NHEADS; ++hh) {
        float wh1r = wh1[hh * N + i];
        if (t < deg) {
            float s = wh1r + wh2[hh * N + colsS[t]];
            s = s > 0.f ? s : 0.2f * s;        // leaky_relu on edge score
            wS[t] = expf(s) - 1.f;
        }
        __syncthreads();
        float acc = 0.f, wsum = 0.f;
        for (int k = 0; k < deg; ++k) {
            float w = wS[k];
            wsum += w;
            acc += w * h_all[(size_t)colsS[k] * 1024 + hh * 256 + t];
        }
        float val = (colsum[hh * 256 + t] + acc) / ((float)NNODES + wsum);
        val = val > 0.f ? val : 0.2f * val;    // leaky_relu on attn@h
        float sq = val * val;
        for (int o = 32; o > 0; o >>= 1) sq += __shfl_down(sq, o);
        if ((t & 63) == 0) red[t >> 6] = sq;
        __syncthreads();
        float nrm = sqrtf(red[0] + red[1] + red[2] + red[3]);
        val = val / fmaxf(nrm, 1e-12f) + bias[hh * 256 + t];
        hsum += val;
        __syncthreads();                        // protect wS/red reuse
    }
    float o = hsum * 0.25f + prev[(size_t)i * 256 + t];
    o = o > 0.f ? o : (expf(o) - 1.f);          // elu
    outp[(size_t)i * 256 + t] = o;
}

extern "C" void kernel_launch(void* const* d_in, const int* in_sizes, int n_in,
                              void* d_out, int out_size, void* d_ws, size_t ws_size,
                              hipStream_t stream)
{
    const float* x  = (const float*)d_in[0];
    const int*   ei = (const int*)d_in[1];
    const float* W1 = (const float*)d_in[2];
    const float* a1 = (const float*)d_in[3];
    const float* b1 = (const float*)d_in[4];
    const float* Wk = (const float*)d_in[5];
    const float* ak = (const float*)d_in[6];
    const float* bk = (const float*)d_in[7];
    const float* pW = (const float*)d_in[8];
    const float* pb = (const float*)d_in[9];
    const int N = NNODES;
    const int E = in_sizes[1] / 2;
    const int* er = ei;
    const int* ec = ei + E;

    float* ws = (float*)d_ws;
    size_t off = 0;
    float* h_all   = ws + off; off += (size_t)N * 1024;
    float* bufA    = ws + off; off += (size_t)N * 256;
    float* bufProj = ws + off; off += (size_t)N * 256;
    float* wh1     = ws + off; off += (size_t)NHEADS * N;
    float* wh2     = ws + off; off += (size_t)NHEADS * N;
    float* colsum  = ws + off; off += 1024;
    int*   cnt     = (int*)(ws + off); off += N;
    int*   cols    = (int*)(ws + off); off += (size_t)N * MAXDEG;
    unsigned int* bitmap = (unsigned int*)(ws + off); off += (size_t)N * N / 32;

    // zero dedupe state each call (ws is not re-poisoned between replays,
    // and our own previous call left it dirty)
    hipMemsetAsync(cnt, 0, N * sizeof(int), stream);
    hipMemsetAsync(bitmap, 0, (size_t)N * N / 8, stream);
    build_csr<<<(E + 255) / 256, 256, 0, stream>>>(er, ec, bitmap, cnt, cols, E);

    for (int l = 0; l < 4; ++l) {
        const float* A  = (l == 0) ? x : bufA;
        int K           = (l == 0) ? 512 : 256;
        const float* W  = (l == 0) ? W1 : Wk + (size_t)(l - 1) * NHEADS * 256 * 256;
        const float* av = (l == 0) ? a1 : ak + (size_t)(l - 1) * NHEADS * 512;
        const float* bv = (l == 0) ? b1 : bk + (size_t)(l - 1) * NHEADS * 256;

        gemm_heads<<<dim3(16, 64), 256, 0, stream>>>(A, W, nullptr, h_all, N, K, 1024);
        if (l == 0)
            gemm_heads<<<dim3(4, 64), 256, 0, stream>>>(x, pW, pb, bufProj, N, 512, 256);
        wh_kernel<<<N, 256, 0, stream>>>(h_all, av, wh1, wh2, N);
        hipMemsetAsync(colsum, 0, 1024 * sizeof(float), stream);
        colsum_kernel<<<dim3(4, 32), 256, 0, stream>>>(h_all, colsum, N);

        const float* prev = (l == 0) ? bufProj : bufA;
        float* outp = (l == 3) ? (float*)d_out : bufA;
        row_attn<<<N, 256, 0, stream>>>(h_all, wh1, wh2, colsum, cnt, cols, bv, prev, outp, N);
    }
}

// Round 2
// 425.778 us; speedup vs baseline: 1.4253x; 1.4253x over previous
//
#include <hip/hip_runtime.h>
#include <hip/hip_bf16.h>
#include <math.h>

#define NNODES 4096
#define NHEADS 4
#define MAXDEG 128

typedef __attribute__((ext_vector_type(8))) short  bf16x8;
typedef __attribute__((ext_vector_type(4))) float  f32x4;
typedef __attribute__((ext_vector_type(4))) unsigned short us4;

__device__ __forceinline__ unsigned short f2bf(float v) {
    unsigned int x = __float_as_uint(v);
    unsigned int r = (x + 0x7fffu + ((x >> 16) & 1u)) >> 16;   // RNE
    return (unsigned short)r;
}

__device__ __forceinline__ void gload_lds16(const unsigned short* g, unsigned short* l) {
    __builtin_amdgcn_global_load_lds(
        (const __attribute__((address_space(1))) unsigned int*)(g),
        (__attribute__((address_space(3))) unsigned int*)(l), 16, 0, 0);
}

// ---------------- CSR build with bitmap dedupe ----------------
__global__ __launch_bounds__(256) void build_csr(
    const int* __restrict__ er, const int* __restrict__ ec,
    unsigned int* __restrict__ bitmap, int* __restrict__ cnt,
    int* __restrict__ cols, int E)
{
    int e = blockIdx.x * 256 + threadIdx.x;
    if (e >= E) return;
    int r = er[e], c = ec[e];
    unsigned int idx = ((unsigned int)r << 12) | (unsigned int)c;
    unsigned int bit = 1u << (idx & 31);
    unsigned int old = atomicOr(&bitmap[idx >> 5], bit);
    if (!(old & bit)) {
        int slot = atomicAdd(&cnt[r], 1);
        if (slot < MAXDEG) cols[r * MAXDEG + slot] = c;
    }
}

// ---------------- fp32 -> bf16 elementwise (vectorized) ----------------
__global__ __launch_bounds__(256) void cvt_bf16(
    const float* __restrict__ in, unsigned short* __restrict__ out, int n4)
{
    int i = blockIdx.x * 256 + threadIdx.x;
    if (i >= n4) return;
    float4 v = *(const float4*)(in + (size_t)i * 4);
    us4 o; o.x = f2bf(v.x); o.y = f2bf(v.y); o.z = f2bf(v.z); o.w = f2bf(v.w);
    *(us4*)(out + (size_t)i * 4) = o;
}

// ---------------- W[h][k][j] fp32 -> Wt[h*256+j][K] bf16 (tiled transpose) ----------------
__global__ __launch_bounds__(256) void transpose_w(
    const float* __restrict__ W, unsigned short* __restrict__ Wt, int K)
{
    __shared__ float tile[32][33];
    int k0 = blockIdx.x * 32;
    int j0 = blockIdx.y * 32;
    int h  = blockIdx.z;
    int tj = threadIdx.x & 31;      // inner (coalesced) index
    int tk = threadIdx.x >> 5;      // 0..7
#pragma unroll
    for (int it = 0; it < 4; ++it) {
        int kl = tk + it * 8;
        tile[kl][tj] = W[(size_t)h * K * 256 + (size_t)(k0 + kl) * 256 + j0 + tj];
    }
    __syncthreads();
#pragma unroll
    for (int it = 0; it < 4; ++it) {
        int jl = tk + it * 8;
        Wt[(size_t)(h * 256 + j0 + jl) * K + k0 + tj] = f2bf(tile[tj][jl]);
    }
}

// ---------------- bf16 MFMA GEMM: C[M,NH] = A[M,K] @ Bt[NH,K]^T ----------------
// 128x128 tile, BK=32, 4 waves (2x2), 4x4 16x16 fragments per wave.
// Staging: global_load_lds w16, linear LDS dest, XOR-swizzled source; reads swizzled.
__global__ __launch_bounds__(256) void gemm_mfma(
    const unsigned short* __restrict__ A, const unsigned short* __restrict__ Bt,
    const float* __restrict__ bias, float* __restrict__ C,
    int M, int K, int NH)
{
    __shared__ unsigned short As[128 * 32];
    __shared__ unsigned short Bs[128 * 32];
    int tid = threadIdx.x;
    int lane = tid & 63;
    int wave = tid >> 6;
    int wr = wave >> 1, wc = wave & 1;
    int tileM = blockIdx.y * 128;
    int tileN = blockIdx.x * 128;

    f32x4 acc[4][4];
#pragma unroll
    for (int m = 0; m < 4; ++m)
#pragma unroll
        for (int n = 0; n < 4; ++n) acc[m][n] = (f32x4){0.f, 0.f, 0.f, 0.f};

    // staging: thread t covers LDS row t/4 (and +64), 16B slot t%4 (linear dest)
    int srow = tid >> 2;
    int sslot = tid & 3;
    int gslot = sslot ^ (srow & 3);             // (srow+64)&3 == srow&3, reuse for both halves
    const unsigned short* gA0 = A + (size_t)(tileM + srow) * K + gslot * 8;
    const unsigned short* gA1 = A + (size_t)(tileM + 64 + srow) * K + gslot * 8;
    const unsigned short* gB0 = Bt + (size_t)(tileN + srow) * K + gslot * 8;
    const unsigned short* gB1 = Bt + (size_t)(tileN + 64 + srow) * K + gslot * 8;
    unsigned short* lA0 = As + tid * 8;
    unsigned short* lA1 = As + 2048 + tid * 8;
    unsigned short* lB0 = Bs + tid * 8;
    unsigned short* lB1 = Bs + 2048 + tid * 8;

    int fr = lane & 15;         // row/col within 16x16 fragment
    int kq = lane >> 4;         // k-slot 0..3 (8 bf16 each)

    for (int k0 = 0; k0 < K; k0 += 32) {
        gload_lds16(gA0, lA0); gload_lds16(gA1, lA1);
        gload_lds16(gB0, lB0); gload_lds16(gB1, lB1);
        gA0 += 32; gA1 += 32; gB0 += 32; gB1 += 32;
        __syncthreads();                        // drains vmcnt before barrier
        bf16x8 af[4], bfr[4];
#pragma unroll
        for (int m = 0; m < 4; ++m) {
            int row = wr * 64 + m * 16 + fr;
            af[m] = *(const bf16x8*)(As + row * 32 + ((kq ^ (row & 3)) << 3));
        }
#pragma unroll
        for (int n = 0; n < 4; ++n) {
            int col = wc * 64 + n * 16 + fr;
            bfr[n] = *(const bf16x8*)(Bs + col * 32 + ((kq ^ (col & 3)) << 3));
        }
#pragma unroll
        for (int m = 0; m < 4; ++m)
#pragma unroll
            for (int n = 0; n < 4; ++n)
                acc[m][n] = __builtin_amdgcn_mfma_f32_16x16x32_bf16(af[m], bfr[n], acc[m][n], 0, 0, 0);
        __syncthreads();
    }

    int crow0 = tileM + wr * 64;
    int ccol0 = tileN + wc * 64;
#pragma unroll
    for (int m = 0; m < 4; ++m)
#pragma unroll
        for (int n = 0; n < 4; ++n) {
            int r0 = crow0 + m * 16 + (lane >> 4) * 4;
            int c  = ccol0 + n * 16 + (lane & 15);
            float bv = bias ? bias[c & 255] : 0.f;
#pragma unroll
            for (int q = 0; q < 4; ++q)
                C[(size_t)(r0 + q) * NH + c] = acc[m][n][q] + bv;
        }
}

// ---------------- wh1/wh2: per (row, head) dot(h_row, a) ----------------
__global__ __launch_bounds__(256) void wh_kernel(
    const float* __restrict__ h_all, const float* __restrict__ a,
    float* __restrict__ wh1, float* __restrict__ wh2, int N)
{
    int i = blockIdx.x;
    int t = threadIdx.x;
    __shared__ float red[8];
    for (int hh = 0; hh < NHEADS; ++hh) {
        float v = h_all[(size_t)i * 1024 + hh * 256 + t];
        float p1 = v * a[hh * 512 + t];
        float p2 = v * a[hh * 512 + 256 + t];
        for (int o = 32; o > 0; o >>= 1) {
            p1 += __shfl_down(p1, o);
            p2 += __shfl_down(p2, o);
        }
        if ((t & 63) == 0) { red[t >> 6] = p1; red[4 + (t >> 6)] = p2; }
        __syncthreads();
        if (t == 0) {
            wh1[hh * N + i] = red[0] + red[1] + red[2] + red[3];
            wh2[hh * N + i] = red[4] + red[5] + red[6] + red[7];
        }
        __syncthreads();
    }
}

// ---------------- column sums of h_all ----------------
__global__ __launch_bounds__(256) void colsum_kernel(
    const float* __restrict__ h_all, float* __restrict__ colsum, int N)
{
    int c = blockIdx.x * 256 + threadIdx.x;
    int r0 = blockIdx.y * 128;
    float s = 0.f;
    for (int r = r0; r < r0 + 128; ++r) s += h_all[(size_t)r * 1024 + c];
    atomicAdd(&colsum[c], s);
}

// ---------------- per-row attention + normalize + head-mean + residual + elu ----------------
__global__ __launch_bounds__(256) void row_attn(
    const float* __restrict__ h_all, const float* __restrict__ wh1,
    const float* __restrict__ wh2, const float* __restrict__ colsum,
    const int* __restrict__ cnt, const int* __restrict__ cols,
    const float* __restrict__ bias, const float* __restrict__ prev,
    float* __restrict__ outp, unsigned short* __restrict__ out_bf, int N)
{
    int i = blockIdx.x;
    int t = threadIdx.x;
    __shared__ int colsS[MAXDEG];
    __shared__ float wS[MAXDEG];
    __shared__ float red[4];
    int deg = cnt[i];
    if (deg > MAXDEG) deg = MAXDEG;
    if (t < deg) colsS[t] = cols[i * MAXDEG + t];
    __syncthreads();

    float hsum = 0.f;
    for (int hh = 0; hh < NHEADS; ++hh) {
        float wh1r = wh1[hh * N + i];
        if (t < deg) {
            float s = wh1r + wh2[hh * N + colsS[t]];
            s = s > 0.f ? s : 0.2f * s;
            wS[t] = expf(s) - 1.f;
        }
        __syncthreads();
        float acc = 0.f, wsum = 0.f;
        for (int k = 0; k < deg; ++k) {
            float w = wS[k];
            wsum += w;
            acc += w * h_all[(size_t)colsS[k] * 1024 + hh * 256 + t];
        }
        float val = (colsum[hh * 256 + t] + acc) / ((float)NNODES + wsum);
        val = val > 0.f ? val : 0.2f * val;
        float sq = val * val;
        for (int o = 32; o > 0; o >>= 1) sq += __shfl_down(sq, o);
        if ((t & 63) == 0) red[t >> 6] = sq;
        __syncthreads();
        float nrm = sqrtf(red[0] + red[1] + red[2] + red[3]);
        val = val / fmaxf(nrm, 1e-12f) + bias[hh * 256 + t];
        hsum += val;
        __syncthreads();
    }
    float o = hsum * 0.25f + prev[(size_t)i * 256 + t];
    o = o > 0.f ? o : (expf(o) - 1.f);
    outp[(size_t)i * 256 + t] = o;
    out_bf[(size_t)i * 256 + t] = f2bf(o);
}

extern "C" void kernel_launch(void* const* d_in, const int* in_sizes, int n_in,
                              void* d_out, int out_size, void* d_ws, size_t ws_size,
                              hipStream_t stream)
{
    const float* x  = (const float*)d_in[0];
    const int*   ei = (const int*)d_in[1];
    const float* W1 = (const float*)d_in[2];
    const float* a1 = (const float*)d_in[3];
    const float* b1 = (const float*)d_in[4];
    const float* Wk = (const float*)d_in[5];
    const float* ak = (const float*)d_in[6];
    const float* bk = (const float*)d_in[7];
    const float* pW = (const float*)d_in[8];
    const float* pb = (const float*)d_in[9];
    const int N = NNODES;
    const int E = in_sizes[1] / 2;
    const int* er = ei;
    const int* ec = ei + E;

    float* ws = (float*)d_ws;
    size_t off = 0;
    float* h_all   = ws + off; off += (size_t)N * 1024;
    float* bufA    = ws + off; off += (size_t)N * 256;
    float* bufProj = ws + off; off += (size_t)N * 256;
    float* wh1     = ws + off; off += (size_t)NHEADS * N;
    float* wh2     = ws + off; off += (size_t)NHEADS * N;
    float* colsum  = ws + off; off += 1024;
    int*   cnt     = (int*)(ws + off); off += N;
    int*   cols    = (int*)(ws + off); off += (size_t)N * MAXDEG;
    unsigned int* bitmap = (unsigned int*)(ws + off); off += (size_t)N * N / 32;
    unsigned short* xb    = (unsigned short*)(ws + off); off += (size_t)N * 512 / 2;
    unsigned short* bufAb = (unsigned short*)(ws + off); off += (size_t)N * 256 / 2;
    unsigned short* Wt    = (unsigned short*)(ws + off); off += (size_t)4 * 256 * 512 / 2;
    unsigned short* pWt   = (unsigned short*)(ws + off); off += (size_t)256 * 512 / 2;

    hipMemsetAsync(cnt, 0, N * sizeof(int), stream);
    hipMemsetAsync(bitmap, 0, (size_t)N * N / 8, stream);
    build_csr<<<(E + 255) / 256, 256, 0, stream>>>(er, ec, bitmap, cnt, cols, E);

    cvt_bf16<<<(N * 512 / 4 + 255) / 256, 256, 0, stream>>>(x, xb, N * 512 / 4);
    transpose_w<<<dim3(512 / 32, 8, 1), 256, 0, stream>>>(pW, pWt, 512);

    for (int l = 0; l < 4; ++l) {
        int K           = (l == 0) ? 512 : 256;
        const float* W  = (l == 0) ? W1 : Wk + (size_t)(l - 1) * NHEADS * 256 * 256;
        const float* av = (l == 0) ? a1 : ak + (size_t)(l - 1) * NHEADS * 512;
        const float* bv = (l == 0) ? b1 : bk + (size_t)(l - 1) * NHEADS * 256;
        const unsigned short* Ab = (l == 0) ? xb : bufAb;

        transpose_w<<<dim3(K / 32, 8, NHEADS), 256, 0, stream>>>(W, Wt, K);
        gemm_mfma<<<dim3(1024 / 128, N / 128), 256, 0, stream>>>(Ab, Wt, nullptr, h_all, N, K, 1024);
        if (l == 0)
            gemm_mfma<<<dim3(256 / 128, N / 128), 256, 0, stream>>>(xb, pWt, pb, bufProj, N, 512, 256);

        wh_kernel<<<N, 256, 0, stream>>>(h_all, av, wh1, wh2, N);
        hipMemsetAsync(colsum, 0, 1024 * sizeof(float), stream);
        colsum_kernel<<<dim3(4, 32), 256, 0, stream>>>(h_all, colsum, N);

        const float* prev = (l == 0) ? bufProj : bufA;
        float* outp = (l == 3) ? (float*)d_out : bufA;
        row_attn<<<N, 256, 0, stream>>>(h_all, wh1, wh2, colsum, cnt, cols, bv, prev, outp, bufAb, N);
    }
}

// Round 3
// 257.098 us; speedup vs baseline: 2.3605x; 1.6561x over previous
//
#include <hip/hip_runtime.h>
#include <hip/hip_bf16.h>
#include <math.h>

#define NNODES 4096
#define NHEADS 4
#define MAXDEG 128

typedef __attribute__((ext_vector_type(8))) short  bf16x8;
typedef __attribute__((ext_vector_type(4))) float  f32x4;
typedef __attribute__((ext_vector_type(4))) unsigned short us4;

__device__ __forceinline__ unsigned short f2bf(float v) {
    unsigned int x = __float_as_uint(v);
    unsigned int r = (x + 0x7fffu + ((x >> 16) & 1u)) >> 16;   // RNE
    return (unsigned short)r;
}

__device__ __forceinline__ void gload_lds16(const unsigned short* g, unsigned short* l) {
    __builtin_amdgcn_global_load_lds(
        (const __attribute__((address_space(1))) unsigned int*)(g),
        (__attribute__((address_space(3))) unsigned int*)(l), 16, 0, 0);
}

// ---------------- CSR build with bitmap dedupe ----------------
__global__ __launch_bounds__(256) void build_csr(
    const int* __restrict__ er, const int* __restrict__ ec,
    unsigned int* __restrict__ bitmap, int* __restrict__ cnt,
    int* __restrict__ cols, int E)
{
    int e = blockIdx.x * 256 + threadIdx.x;
    if (e >= E) return;
    int r = er[e], c = ec[e];
    unsigned int idx = ((unsigned int)r << 12) | (unsigned int)c;
    unsigned int bit = 1u << (idx & 31);
    unsigned int old = atomicOr(&bitmap[idx >> 5], bit);
    if (!(old & bit)) {
        int slot = atomicAdd(&cnt[r], 1);
        if (slot < MAXDEG) cols[r * MAXDEG + slot] = c;
    }
}

// ---------------- fp32 -> bf16 elementwise (vectorized) ----------------
__global__ __launch_bounds__(256) void cvt_bf16(
    const float* __restrict__ in, unsigned short* __restrict__ out, int n4)
{
    int i = blockIdx.x * 256 + threadIdx.x;
    if (i >= n4) return;
    float4 v = *(const float4*)(in + (size_t)i * 4);
    us4 o; o.x = f2bf(v.x); o.y = f2bf(v.y); o.z = f2bf(v.z); o.w = f2bf(v.w);
    *(us4*)(out + (size_t)i * 4) = o;
}

// ---------------- W[h][k][j] fp32 -> Wt[h*256+j][K] bf16 (tiled transpose) ----------------
__global__ __launch_bounds__(256) void transpose_w(
    const float* __restrict__ W, unsigned short* __restrict__ Wt, int K)
{
    __shared__ float tile[32][33];
    int k0 = blockIdx.x * 32;
    int j0 = blockIdx.y * 32;
    int h  = blockIdx.z;
    int tj = threadIdx.x & 31;
    int tk = threadIdx.x >> 5;
#pragma unroll
    for (int it = 0; it < 4; ++it) {
        int kl = tk + it * 8;
        tile[kl][tj] = W[(size_t)h * K * 256 + (size_t)(k0 + kl) * 256 + j0 + tj];
    }
    __syncthreads();
#pragma unroll
    for (int it = 0; it < 4; ++it) {
        int jl = tk + it * 8;
        Wt[(size_t)(h * 256 + j0 + jl) * K + k0 + tj] = f2bf(tile[tj][jl]);
    }
}

// ---------------- bf16 MFMA GEMM with optional fused epilogue ----------------
// FUSED=1: C -> bf16 h_all, and fused wh1/wh2 (row dot a) + colsum atomics.
// FUSED=0: C -> fp32 with bias (proj path).
template <int FUSED>
__global__ __launch_bounds__(256) void gemm_mfma(
    const unsigned short* __restrict__ A, const unsigned short* __restrict__ Bt,
    const float* __restrict__ bias, float* __restrict__ Cf,
    unsigned short* __restrict__ Cbf, const float* __restrict__ av,
    float* __restrict__ wh1, float* __restrict__ wh2, float* __restrict__ colsum,
    int M, int K, int NH)
{
    __shared__ unsigned short As[128 * 32];
    __shared__ unsigned short Bs[128 * 32];
    int tid = threadIdx.x;
    int lane = tid & 63;
    int wave = tid >> 6;
    int wr = wave >> 1, wc = wave & 1;
    int tileM = blockIdx.y * 128;
    int tileN = blockIdx.x * 128;

    f32x4 acc[4][4];
#pragma unroll
    for (int m = 0; m < 4; ++m)
#pragma unroll
        for (int n = 0; n < 4; ++n) acc[m][n] = (f32x4){0.f, 0.f, 0.f, 0.f};

    int srow = tid >> 2;
    int sslot = tid & 3;
    int gslot = sslot ^ (srow & 3);
    const unsigned short* gA0 = A + (size_t)(tileM + srow) * K + gslot * 8;
    const unsigned short* gA1 = A + (size_t)(tileM + 64 + srow) * K + gslot * 8;
    const unsigned short* gB0 = Bt + (size_t)(tileN + srow) * K + gslot * 8;
    const unsigned short* gB1 = Bt + (size_t)(tileN + 64 + srow) * K + gslot * 8;
    unsigned short* lA0 = As + tid * 8;
    unsigned short* lA1 = As + 2048 + tid * 8;
    unsigned short* lB0 = Bs + tid * 8;
    unsigned short* lB1 = Bs + 2048 + tid * 8;

    int fr = lane & 15;
    int kq = lane >> 4;

    for (int k0 = 0; k0 < K; k0 += 32) {
        gload_lds16(gA0, lA0); gload_lds16(gA1, lA1);
        gload_lds16(gB0, lB0); gload_lds16(gB1, lB1);
        gA0 += 32; gA1 += 32; gB0 += 32; gB1 += 32;
        __syncthreads();
        bf16x8 af[4], bfr[4];
#pragma unroll
        for (int m = 0; m < 4; ++m) {
            int row = wr * 64 + m * 16 + fr;
            af[m] = *(const bf16x8*)(As + row * 32 + ((kq ^ (row & 3)) << 3));
        }
#pragma unroll
        for (int n = 0; n < 4; ++n) {
            int col = wc * 64 + n * 16 + fr;
            bfr[n] = *(const bf16x8*)(Bs + col * 32 + ((kq ^ (col & 3)) << 3));
        }
#pragma unroll
        for (int m = 0; m < 4; ++m)
#pragma unroll
            for (int n = 0; n < 4; ++n)
                acc[m][n] = __builtin_amdgcn_mfma_f32_16x16x32_bf16(af[m], bfr[n], acc[m][n], 0, 0, 0);
        __syncthreads();
    }

    int crow0 = tileM + wr * 64;
    int ccol0 = tileN + wc * 64;

    if (FUSED) {
        int head = tileN >> 8;          // 128-wide tile lies within one 256-wide head
        // --- colsum atomics (reduce over row-groups then one atomic per col) ---
#pragma unroll
        for (int n = 0; n < 4; ++n) {
            float s = 0.f;
#pragma unroll
            for (int m = 0; m < 4; ++m)
#pragma unroll
                for (int q = 0; q < 4; ++q) s += acc[m][n][q];
            s += __shfl_xor(s, 16);
            s += __shfl_xor(s, 32);
            if ((lane >> 4) == 0)
                atomicAdd(colsum + ccol0 + n * 16 + (lane & 15), s);
        }
        // --- wh1/wh2 fused row-dots ---
        float c1[4], c2[4];
#pragma unroll
        for (int n = 0; n < 4; ++n) {
            int j = (ccol0 + n * 16 + (lane & 15)) & 255;
            c1[n] = av[head * 512 + j];
            c2[n] = av[head * 512 + 256 + j];
        }
#pragma unroll
        for (int m = 0; m < 4; ++m)
#pragma unroll
            for (int q = 0; q < 4; ++q) {
                float p1 = 0.f, p2 = 0.f;
#pragma unroll
                for (int n = 0; n < 4; ++n) {
                    p1 += acc[m][n][q] * c1[n];
                    p2 += acc[m][n][q] * c2[n];
                }
#pragma unroll
                for (int o = 1; o < 16; o <<= 1) {
                    p1 += __shfl_xor(p1, o);
                    p2 += __shfl_xor(p2, o);
                }
                if ((lane & 15) == 0) {
                    int r = crow0 + m * 16 + (lane >> 4) * 4 + q;
                    atomicAdd(wh1 + head * NNODES + r, p1);
                    atomicAdd(wh2 + head * NNODES + r, p2);
                }
            }
        // --- bf16 C store ---
#pragma unroll
        for (int m = 0; m < 4; ++m)
#pragma unroll
            for (int n = 0; n < 4; ++n) {
                int r0 = crow0 + m * 16 + (lane >> 4) * 4;
                int c  = ccol0 + n * 16 + (lane & 15);
#pragma unroll
                for (int q = 0; q < 4; ++q)
                    Cbf[(size_t)(r0 + q) * NH + c] = f2bf(acc[m][n][q]);
            }
    } else {
#pragma unroll
        for (int m = 0; m < 4; ++m)
#pragma unroll
            for (int n = 0; n < 4; ++n) {
                int r0 = crow0 + m * 16 + (lane >> 4) * 4;
                int c  = ccol0 + n * 16 + (lane & 15);
                float bv = bias ? bias[c & 255] : 0.f;
#pragma unroll
                for (int q = 0; q < 4; ++q)
                    Cf[(size_t)(r0 + q) * NH + c] = acc[m][n][q] + bv;
            }
    }
}

// ---------------- per-row attention: 2 heads per pass, uint(2xbf16) gather ----------------
__global__ __launch_bounds__(256) void row_attn(
    const unsigned short* __restrict__ h_bf, const float* __restrict__ wh1,
    const float* __restrict__ wh2, const float* __restrict__ colsum,
    const int* __restrict__ cnt, const int* __restrict__ cols,
    const float* __restrict__ bias, const float* __restrict__ prev,
    float* __restrict__ outp, unsigned short* __restrict__ out_bf, int N)
{
    int i = blockIdx.x;
    int t = threadIdx.x;
    int g = t >> 7;           // head parity (0/1)
    int u = t & 127;          // feature-pair index
    int wv = t >> 6;          // wave id
    __shared__ int colsS[MAXDEG];
    __shared__ float wS[2][MAXDEG];
    __shared__ float red[4];
    __shared__ float fsum[512];
    int deg = cnt[i];
    if (deg > MAXDEG) deg = MAXDEG;
    if (t < deg) colsS[t] = cols[i * MAXDEG + t];
    __syncthreads();

#pragma unroll
    for (int p = 0; p < 2; ++p) {
        int hh = 2 * p + g;
        // edge weights for this half's head
        if (u < deg) {
            float s = wh1[hh * N + i] + wh2[hh * N + colsS[u]];
            s = s > 0.f ? s : 0.2f * s;
            wS[g][u] = expf(s) - 1.f;
        }
        __syncthreads();
        float acc0 = 0.f, acc1 = 0.f, wsum = 0.f;
        const unsigned short* hbase = h_bf + hh * 256 + 2 * u;
        for (int k = 0; k < deg; ++k) {
            float w = wS[g][k];
            unsigned int v = *(const unsigned int*)(hbase + (size_t)colsS[k] * 1024);
            wsum += w;
            acc0 += w * __uint_as_float(v << 16);
            acc1 += w * __uint_as_float(v & 0xffff0000u);
        }
        float inv = 1.f / ((float)NNODES + wsum);
        float val0 = (colsum[hh * 256 + 2 * u] + acc0) * inv;
        float val1 = (colsum[hh * 256 + 2 * u + 1] + acc1) * inv;
        val0 = val0 > 0.f ? val0 : 0.2f * val0;
        val1 = val1 > 0.f ? val1 : 0.2f * val1;
        float sq = val0 * val0 + val1 * val1;
#pragma unroll
        for (int o = 1; o < 64; o <<= 1) sq += __shfl_xor(sq, o);
        if ((t & 63) == 0) red[wv] = sq;
        __syncthreads();
        float nrm = sqrtf(red[2 * g] + red[2 * g + 1]);
        float rinv = 1.f / fmaxf(nrm, 1e-12f);
        val0 = val0 * rinv + bias[hh * 256 + 2 * u];
        val1 = val1 * rinv + bias[hh * 256 + 2 * u + 1];
        if (p == 0) {
            fsum[g * 256 + 2 * u]     = val0;
            fsum[g * 256 + 2 * u + 1] = val1;
        } else {
            fsum[g * 256 + 2 * u]     += val0;
            fsum[g * 256 + 2 * u + 1] += val1;
        }
        __syncthreads();        // protect wS/red for next pass, fsum for final read
    }
    float o = (fsum[t] + fsum[256 + t]) * 0.25f + prev[(size_t)i * 256 + t];
    o = o > 0.f ? o : (expf(o) - 1.f);
    outp[(size_t)i * 256 + t] = o;
    out_bf[(size_t)i * 256 + t] = f2bf(o);
}

extern "C" void kernel_launch(void* const* d_in, const int* in_sizes, int n_in,
                              void* d_out, int out_size, void* d_ws, size_t ws_size,
                              hipStream_t stream)
{
    const float* x  = (const float*)d_in[0];
    const int*   ei = (const int*)d_in[1];
    const float* W1 = (const float*)d_in[2];
    const float* a1 = (const float*)d_in[3];
    const float* b1 = (const float*)d_in[4];
    const float* Wk = (const float*)d_in[5];
    const float* ak = (const float*)d_in[6];
    const float* bk = (const float*)d_in[7];
    const float* pW = (const float*)d_in[8];
    const float* pb = (const float*)d_in[9];
    const int N = NNODES;
    const int E = in_sizes[1] / 2;
    const int* er = ei;
    const int* ec = ei + E;

    float* ws = (float*)d_ws;
    size_t off = 0;
    float* bufA    = ws + off; off += (size_t)N * 256;
    float* bufProj = ws + off; off += (size_t)N * 256;
    float* wh1     = ws + off; off += (size_t)NHEADS * N;
    float* wh2     = ws + off; off += (size_t)NHEADS * N;
    float* colsum  = ws + off; off += 1024;
    int*   cnt     = (int*)(ws + off); off += N;
    int*   cols    = (int*)(ws + off); off += (size_t)N * MAXDEG;
    unsigned int* bitmap = (unsigned int*)(ws + off); off += (size_t)N * N / 32;
    unsigned short* h_bf  = (unsigned short*)(ws + off); off += (size_t)N * 1024 / 2;
    unsigned short* xb    = (unsigned short*)(ws + off); off += (size_t)N * 512 / 2;
    unsigned short* bufAb = (unsigned short*)(ws + off); off += (size_t)N * 256 / 2;
    unsigned short* Wt1   = (unsigned short*)(ws + off); off += (size_t)4 * 256 * 512 / 2;
    unsigned short* Wtk   = (unsigned short*)(ws + off); off += (size_t)12 * 256 * 256 / 2;
    unsigned short* pWt   = (unsigned short*)(ws + off); off += (size_t)256 * 512 / 2;

    hipMemsetAsync(cnt, 0, N * sizeof(int), stream);
    hipMemsetAsync(bitmap, 0, (size_t)N * N / 8, stream);
    build_csr<<<(E + 255) / 256, 256, 0, stream>>>(er, ec, bitmap, cnt, cols, E);

    cvt_bf16<<<(N * 512 / 4 + 255) / 256, 256, 0, stream>>>(x, xb, N * 512 / 4);
    transpose_w<<<dim3(16, 8, 1), 256, 0, stream>>>(pW, pWt, 512);
    transpose_w<<<dim3(16, 8, 4), 256, 0, stream>>>(W1, Wt1, 512);
    transpose_w<<<dim3(8, 8, 12), 256, 0, stream>>>(Wk, Wtk, 256);   // 3 layers x 4 heads

    for (int l = 0; l < 4; ++l) {
        int K = (l == 0) ? 512 : 256;
        const unsigned short* Wt = (l == 0) ? Wt1 : Wtk + (size_t)(l - 1) * 4 * 256 * 256;
        const float* av = (l == 0) ? a1 : ak + (size_t)(l - 1) * NHEADS * 512;
        const float* bv = (l == 0) ? b1 : bk + (size_t)(l - 1) * NHEADS * 256;
        const unsigned short* Ab = (l == 0) ? xb : bufAb;

        // zero wh1 | wh2 | colsum (contiguous) for the fused-epilogue atomics
        hipMemsetAsync(wh1, 0, (2 * NHEADS * N + 1024) * sizeof(float), stream);
        gemm_mfma<1><<<dim3(8, 32), 256, 0, stream>>>(
            Ab, Wt, nullptr, nullptr, h_bf, av, wh1, wh2, colsum, N, K, 1024);
        if (l == 0)
            gemm_mfma<0><<<dim3(2, 32), 256, 0, stream>>>(
                xb, pWt, pb, bufProj, nullptr, nullptr, nullptr, nullptr, nullptr, N, 512, 256);

        const float* prev = (l == 0) ? bufProj : bufA;
        float* outp = (l == 3) ? (float*)d_out : bufA;
        row_attn<<<N, 256, 0, stream>>>(h_bf, wh1, wh2, colsum, cnt, cols, bv, prev, outp, bufAb, N);
    }
}

// Round 4
// 232.056 us; speedup vs baseline: 2.6152x; 1.1079x over previous
//
#include <hip/hip_runtime.h>
#include <hip/hip_bf16.h>
#include <math.h>

#define NNODES 4096
#define NHEADS 4
#define MAXDEG 128

typedef __attribute__((ext_vector_type(8))) short  bf16x8;
typedef __attribute__((ext_vector_type(4))) float  f32x4;
typedef __attribute__((ext_vector_type(4))) unsigned short us4;

__device__ __forceinline__ unsigned short f2bf(float v) {
    unsigned int x = __float_as_uint(v);
    unsigned int r = (x + 0x7fffu + ((x >> 16) & 1u)) >> 16;   // RNE
    return (unsigned short)r;
}

__device__ __forceinline__ void gload_lds16(const unsigned short* g, unsigned short* l) {
    __builtin_amdgcn_global_load_lds(
        (const __attribute__((address_space(1))) unsigned int*)(g),
        (__attribute__((address_space(3))) unsigned int*)(l), 16, 0, 0);
}

// ---------------- CSR build with bitmap dedupe ----------------
__global__ __launch_bounds__(256) void build_csr(
    const int* __restrict__ er, const int* __restrict__ ec,
    unsigned int* __restrict__ bitmap, int* __restrict__ cnt,
    int* __restrict__ cols, int E)
{
    int e = blockIdx.x * 256 + threadIdx.x;
    if (e >= E) return;
    int r = er[e], c = ec[e];
    unsigned int idx = ((unsigned int)r << 12) | (unsigned int)c;
    unsigned int bit = 1u << (idx & 31);
    unsigned int old = atomicOr(&bitmap[idx >> 5], bit);
    if (!(old & bit)) {
        int slot = atomicAdd(&cnt[r], 1);
        if (slot < MAXDEG) cols[r * MAXDEG + slot] = c;
    }
}

// ---------------- fp32 -> bf16 elementwise (vectorized) ----------------
__global__ __launch_bounds__(256) void cvt_bf16(
    const float* __restrict__ in, unsigned short* __restrict__ out, int n4)
{
    int i = blockIdx.x * 256 + threadIdx.x;
    if (i >= n4) return;
    float4 v = *(const float4*)(in + (size_t)i * 4);
    us4 o; o.x = f2bf(v.x); o.y = f2bf(v.y); o.z = f2bf(v.z); o.w = f2bf(v.w);
    *(us4*)(out + (size_t)i * 4) = o;
}

// ---------------- W[h][k][j] fp32 -> Wt[h*256+j][K] bf16 (tiled transpose) ----------------
__global__ __launch_bounds__(256) void transpose_w(
    const float* __restrict__ W, unsigned short* __restrict__ Wt, int K)
{
    __shared__ float tile[32][33];
    int k0 = blockIdx.x * 32;
    int j0 = blockIdx.y * 32;
    int h  = blockIdx.z;
    int tj = threadIdx.x & 31;
    int tk = threadIdx.x >> 5;
#pragma unroll
    for (int it = 0; it < 4; ++it) {
        int kl = tk + it * 8;
        tile[kl][tj] = W[(size_t)h * K * 256 + (size_t)(k0 + kl) * 256 + j0 + tj];
    }
    __syncthreads();
#pragma unroll
    for (int it = 0; it < 4; ++it) {
        int jl = tk + it * 8;
        Wt[(size_t)(h * 256 + j0 + jl) * K + k0 + tj] = f2bf(tile[tj][jl]);
    }
}

// ---------------- bf16 MFMA GEMM, 64x64 tile, BK=64, 4 waves (2x2 of 32x32) ----
// Main blocks (bn<16): h_all slice -> bf16 + fused wh1/wh2 + colsum atomics.
// Proj blocks (bn>=16, HASPROJ only): fp32 + bias into Cproj (stride 256).
template <int HASPROJ>
__global__ __launch_bounds__(256) void gemm_mfma(
    const unsigned short* __restrict__ A, const unsigned short* __restrict__ Bt,
    const unsigned short* __restrict__ pBt, const float* __restrict__ pb,
    float* __restrict__ Cproj, unsigned short* __restrict__ Cbf,
    const float* __restrict__ av, float* __restrict__ wh1, float* __restrict__ wh2,
    float* __restrict__ colsum, int K)
{
    __shared__ unsigned short As[64 * 64];   // 64 rows x 128B
    __shared__ unsigned short Bs[64 * 64];
    int tid = threadIdx.x;
    int lane = tid & 63;
    int wave = tid >> 6;
    int wr = wave >> 1, wc = wave & 1;
    int bn = blockIdx.x, bm = blockIdx.y;
    int tileM = bm * 64;
    bool isProj = HASPROJ && (bn >= 16);
    const unsigned short* B = isProj ? pBt + (size_t)(bn - 16) * 64 * K
                                     : Bt + (size_t)bn * 64 * K;

    f32x4 acc[2][2];
#pragma unroll
    for (int m = 0; m < 2; ++m)
#pragma unroll
        for (int n = 0; n < 2; ++n) acc[m][n] = (f32x4){0.f, 0.f, 0.f, 0.f};

    // staging: thread covers (row = tid>>3, slot = tid&7) and (row+32, same slot)
    int srow = tid >> 3;
    int sslot = tid & 7;
    int gslot = sslot ^ (srow & 7);          // (srow+32)&7 == srow&7
    const unsigned short* gA0 = A + (size_t)(tileM + srow) * K + gslot * 8;
    const unsigned short* gA1 = A + (size_t)(tileM + 32 + srow) * K + gslot * 8;
    const unsigned short* gB0 = B + (size_t)srow * K + gslot * 8;
    const unsigned short* gB1 = B + (size_t)(32 + srow) * K + gslot * 8;
    unsigned short* lA0 = As + tid * 8;
    unsigned short* lA1 = As + 2048 + tid * 8;
    unsigned short* lB0 = Bs + tid * 8;
    unsigned short* lB1 = Bs + 2048 + tid * 8;

    int fr = lane & 15;
    int kq = lane >> 4;

    for (int k0 = 0; k0 < K; k0 += 64) {
        gload_lds16(gA0, lA0); gload_lds16(gA1, lA1);
        gload_lds16(gB0, lB0); gload_lds16(gB1, lB1);
        gA0 += 64; gA1 += 64; gB0 += 64; gB1 += 64;
        __syncthreads();
        bf16x8 af[2][2], bfr[2][2];
#pragma unroll
        for (int m = 0; m < 2; ++m) {
            int row = wr * 32 + m * 16 + fr;
#pragma unroll
            for (int ks = 0; ks < 2; ++ks) {
                int sl = (ks * 4 + kq) ^ (row & 7);
                af[m][ks] = *(const bf16x8*)(As + row * 64 + sl * 8);
            }
        }
#pragma unroll
        for (int n = 0; n < 2; ++n) {
            int col = wc * 32 + n * 16 + fr;
#pragma unroll
            for (int ks = 0; ks < 2; ++ks) {
                int sl = (ks * 4 + kq) ^ (col & 7);
                bfr[n][ks] = *(const bf16x8*)(Bs + col * 64 + sl * 8);
            }
        }
#pragma unroll
        for (int m = 0; m < 2; ++m)
#pragma unroll
            for (int n = 0; n < 2; ++n)
#pragma unroll
                for (int ks = 0; ks < 2; ++ks)
                    acc[m][n] = __builtin_amdgcn_mfma_f32_16x16x32_bf16(
                        af[m][ks], bfr[n][ks], acc[m][n], 0, 0, 0);
        __syncthreads();
    }

    int crow0 = tileM + wr * 32;

    if (!isProj) {
        int ccol0 = bn * 64 + wc * 32;
        int head = bn >> 2;
        // colsum atomics: sum this wave's 32 rows per column
#pragma unroll
        for (int n = 0; n < 2; ++n) {
            float s = 0.f;
#pragma unroll
            for (int m = 0; m < 2; ++m)
#pragma unroll
                for (int q = 0; q < 4; ++q) s += acc[m][n][q];
            s += __shfl_xor(s, 16);
            s += __shfl_xor(s, 32);
            if (kq == 0)
                atomicAdd(colsum + ccol0 + n * 16 + fr, s);
        }
        // wh1/wh2 fused row-dots
        float c1[2], c2[2];
#pragma unroll
        for (int n = 0; n < 2; ++n) {
            int j = (ccol0 + n * 16 + fr) & 255;
            c1[n] = av[head * 512 + j];
            c2[n] = av[head * 512 + 256 + j];
        }
#pragma unroll
        for (int m = 0; m < 2; ++m)
#pragma unroll
            for (int q = 0; q < 4; ++q) {
                float p1 = 0.f, p2 = 0.f;
#pragma unroll
                for (int n = 0; n < 2; ++n) {
                    p1 += acc[m][n][q] * c1[n];
                    p2 += acc[m][n][q] * c2[n];
                }
#pragma unroll
                for (int o = 1; o < 16; o <<= 1) {
                    p1 += __shfl_xor(p1, o);
                    p2 += __shfl_xor(p2, o);
                }
                if (fr == 0) {
                    int r = crow0 + m * 16 + kq * 4 + q;
                    atomicAdd(wh1 + head * NNODES + r, p1);
                    atomicAdd(wh2 + head * NNODES + r, p2);
                }
            }
        // bf16 C store (stride 1024)
#pragma unroll
        for (int m = 0; m < 2; ++m)
#pragma unroll
            for (int n = 0; n < 2; ++n) {
                int r0 = crow0 + m * 16 + kq * 4;
                int c  = ccol0 + n * 16 + fr;
#pragma unroll
                for (int q = 0; q < 4; ++q)
                    Cbf[(size_t)(r0 + q) * 1024 + c] = f2bf(acc[m][n][q]);
            }
    } else {
        int pcol0 = (bn - 16) * 64 + wc * 32;
#pragma unroll
        for (int m = 0; m < 2; ++m)
#pragma unroll
            for (int n = 0; n < 2; ++n) {
                int r0 = crow0 + m * 16 + kq * 4;
                int c  = pcol0 + n * 16 + fr;
                float bv = pb[c & 255];
#pragma unroll
                for (int q = 0; q < 4; ++q)
                    Cproj[(size_t)(r0 + q) * 256 + c] = acc[m][n][q] + bv;
            }
    }
}

// ---------------- per-row attention: all 4 heads in one gather pass ----------------
// wave h = head h; lane f covers features 4f..4f+3 (uint2 = 4 bf16 per neighbor).
__global__ __launch_bounds__(256) void row_attn(
    const unsigned short* __restrict__ h_bf, const float* __restrict__ wh1,
    const float* __restrict__ wh2, const float* __restrict__ colsum,
    const int* __restrict__ cnt, const int* __restrict__ cols,
    const float* __restrict__ bias, const float* __restrict__ prev,
    float* __restrict__ outp, unsigned short* __restrict__ out_bf, int N)
{
    int i = blockIdx.x;
    int t = threadIdx.x;
    int h = t >> 6, f = t & 63;
    __shared__ int colsS[MAXDEG];
    __shared__ float wS[4][MAXDEG];
    __shared__ float fsum[1024];
    int deg = cnt[i];
    if (deg > MAXDEG) deg = MAXDEG;
    if (t < deg) colsS[t] = cols[i * MAXDEG + t];
    __syncthreads();

    {   // edge weights for all 4 heads: 2 head-pairs x 128 threads
        int k = t & 127;
        int hh0 = t >> 7;
#pragma unroll
        for (int p = 0; p < 2; ++p) {
            int hh = 2 * p + hh0;
            if (k < deg) {
                float s = wh1[hh * N + i] + wh2[hh * N + colsS[k]];
                s = s > 0.f ? s : 0.2f * s;
                wS[hh][k] = expf(s) - 1.f;
            }
        }
    }
    __syncthreads();

    float a0 = 0.f, a1 = 0.f, a2 = 0.f, a3 = 0.f, wsum = 0.f;
    const unsigned short* hb = h_bf + h * 256 + f * 4;
    for (int k = 0; k < deg; ++k) {
        float w = wS[h][k];
        uint2 v = *(const uint2*)(hb + (size_t)colsS[k] * 1024);
        wsum += w;
        a0 += w * __uint_as_float(v.x << 16);
        a1 += w * __uint_as_float(v.x & 0xffff0000u);
        a2 += w * __uint_as_float(v.y << 16);
        a3 += w * __uint_as_float(v.y & 0xffff0000u);
    }
    float inv = 1.f / ((float)NNODES + wsum);
    float4 cs = *(const float4*)(colsum + h * 256 + f * 4);
    float v0 = (cs.x + a0) * inv, v1 = (cs.y + a1) * inv;
    float v2 = (cs.z + a2) * inv, v3 = (cs.w + a3) * inv;
    v0 = v0 > 0.f ? v0 : 0.2f * v0;
    v1 = v1 > 0.f ? v1 : 0.2f * v1;
    v2 = v2 > 0.f ? v2 : 0.2f * v2;
    v3 = v3 > 0.f ? v3 : 0.2f * v3;
    float sq = v0 * v0 + v1 * v1 + v2 * v2 + v3 * v3;
#pragma unroll
    for (int o = 1; o < 64; o <<= 1) sq += __shfl_xor(sq, o);
    float rinv = 1.f / fmaxf(sqrtf(sq), 1e-12f);
    float4 bb = *(const float4*)(bias + h * 256 + f * 4);
    f32x4 fv;
    fv[0] = v0 * rinv + bb.x; fv[1] = v1 * rinv + bb.y;
    fv[2] = v2 * rinv + bb.z; fv[3] = v3 * rinv + bb.w;
    *(f32x4*)(fsum + h * 256 + f * 4) = fv;
    __syncthreads();
    float o = (fsum[t] + fsum[256 + t] + fsum[512 + t] + fsum[768 + t]) * 0.25f
              + prev[(size_t)i * 256 + t];
    o = o > 0.f ? o : (expf(o) - 1.f);
    outp[(size_t)i * 256 + t] = o;
    out_bf[(size_t)i * 256 + t] = f2bf(o);
}

extern "C" void kernel_launch(void* const* d_in, const int* in_sizes, int n_in,
                              void* d_out, int out_size, void* d_ws, size_t ws_size,
                              hipStream_t stream)
{
    const float* x  = (const float*)d_in[0];
    const int*   ei = (const int*)d_in[1];
    const float* W1 = (const float*)d_in[2];
    const float* a1 = (const float*)d_in[3];
    const float* b1 = (const float*)d_in[4];
    const float* Wk = (const float*)d_in[5];
    const float* ak = (const float*)d_in[6];
    const float* bk = (const float*)d_in[7];
    const float* pW = (const float*)d_in[8];
    const float* pb = (const float*)d_in[9];
    const int N = NNODES;
    const int E = in_sizes[1] / 2;
    const int* er = ei;
    const int* ec = ei + E;

    float* ws = (float*)d_ws;
    size_t off = 0;
    float* bufA    = ws + off; off += (size_t)N * 256;
    float* bufProj = ws + off; off += (size_t)N * 256;
    float* wh1     = ws + off; off += (size_t)NHEADS * N;
    float* wh2     = ws + off; off += (size_t)NHEADS * N;
    float* colsum  = ws + off; off += 1024;
    int*   cnt     = (int*)(ws + off); off += N;
    int*   cols    = (int*)(ws + off); off += (size_t)N * MAXDEG;
    unsigned int* bitmap = (unsigned int*)(ws + off); off += (size_t)N * N / 32;
    unsigned short* h_bf  = (unsigned short*)(ws + off); off += (size_t)N * 1024 / 2;
    unsigned short* xb    = (unsigned short*)(ws + off); off += (size_t)N * 512 / 2;
    unsigned short* bufAb = (unsigned short*)(ws + off); off += (size_t)N * 256 / 2;
    unsigned short* Wt1   = (unsigned short*)(ws + off); off += (size_t)4 * 256 * 512 / 2;
    unsigned short* Wtk   = (unsigned short*)(ws + off); off += (size_t)12 * 256 * 256 / 2;
    unsigned short* pWt   = (unsigned short*)(ws + off); off += (size_t)256 * 512 / 2;

    hipMemsetAsync(cnt, 0, N * sizeof(int), stream);
    hipMemsetAsync(bitmap, 0, (size_t)N * N / 8, stream);
    build_csr<<<(E + 255) / 256, 256, 0, stream>>>(er, ec, bitmap, cnt, cols, E);

    cvt_bf16<<<(N * 512 / 4 + 255) / 256, 256, 0, stream>>>(x, xb, N * 512 / 4);
    transpose_w<<<dim3(16, 8, 1), 256, 0, stream>>>(pW, pWt, 512);
    transpose_w<<<dim3(16, 8, 4), 256, 0, stream>>>(W1, Wt1, 512);
    transpose_w<<<dim3(8, 8, 12), 256, 0, stream>>>(Wk, Wtk, 256);

    for (int l = 0; l < 4; ++l) {
        int K = (l == 0) ? 512 : 256;
        const unsigned short* Wt = (l == 0) ? Wt1 : Wtk + (size_t)(l - 1) * 4 * 256 * 256;
        const float* av = (l == 0) ? a1 : ak + (size_t)(l - 1) * NHEADS * 512;
        const float* bv = (l == 0) ? b1 : bk + (size_t)(l - 1) * NHEADS * 256;
        const unsigned short* Ab = (l == 0) ? xb : bufAb;

        // zero wh1 | wh2 | colsum (contiguous) for the fused-epilogue atomics
        hipMemsetAsync(wh1, 0, (2 * NHEADS * N + 1024) * sizeof(float), stream);
        if (l == 0)
            gemm_mfma<1><<<dim3(20, 64), 256, 0, stream>>>(
                Ab, Wt, pWt, pb, bufProj, h_bf, av, wh1, wh2, colsum, K);
        else
            gemm_mfma<0><<<dim3(16, 64), 256, 0, stream>>>(
                Ab, Wt, nullptr, nullptr, nullptr, h_bf, av, wh1, wh2, colsum, K);

        const float* prev = (l == 0) ? bufProj : bufA;
        float* outp = (l == 3) ? (float*)d_out : bufA;
        row_attn<<<N, 256, 0, stream>>>(h_bf, wh1, wh2, colsum, cnt, cols, bv, prev, outp, bufAb, N);
    }
}